// Round 1
// baseline (1391.741 us; speedup 1.0000x reference)
//
#include <hip/hip_runtime.h>
#include <cmath>

#define N_PTS 200000
#define HD 64
#define CD 128
#define KEEP 63

typedef __bf16 bf16;
typedef __bf16 bf16x4 __attribute__((ext_vector_type(4)));
typedef __bf16 bf16x8 __attribute__((ext_vector_type(8)));
typedef float f32x4 __attribute__((ext_vector_type(4)));
typedef float f32x16 __attribute__((ext_vector_type(16)));

__device__ __forceinline__ float elu_f(float v) { return v > 0.f ? v : expm1f(v); }

// ---------------------------------------------------------------------------
// K0: prep WbT[k][o][i] = Wb[k][i][o] (bf16), WcT[c][h] = Wc[h][c] (bf16)
// ---------------------------------------------------------------------------
__global__ __launch_bounds__(256) void k_prep(const float* __restrict__ Wb,
                                              const float* __restrict__ Wc,
                                              bf16* __restrict__ WbT,
                                              bf16* __restrict__ WcT) {
    int idx = blockIdx.x * 256 + threadIdx.x;
    if (idx < KEEP * HD * HD) {
        int k = idx >> 12;          // /4096
        int rem = idx & 4095;
        int o = rem >> 6, i = rem & 63;
        WbT[idx] = (bf16)Wb[(k * HD + i) * HD + o];
    } else {
        int e = idx - KEEP * HD * HD;
        if (e < CD * HD) {
            int c = e >> 6, h = e & 63;
            WcT[e] = (bf16)Wc[h * CD + c];
        }
    }
}

// ---------------------------------------------------------------------------
// K1: f[n][h] = elu( elu(x[n]+y[n]) @ Wa )  stored as bf16.  64 pts / block.
// ---------------------------------------------------------------------------
__global__ __launch_bounds__(256) void k_stage1(const float* __restrict__ x,
                                                const float* __restrict__ y,
                                                const float* __restrict__ Wa,
                                                bf16* __restrict__ f) {
    __shared__ float sWa[CD * HD];      // 32 KB, [c][h] row-major
    __shared__ float gbuf[64 * 129];    // 33 KB, pad +1 to kill bank conflicts
    int tid = threadIdx.x;
    int p0 = blockIdx.x * 64;

    for (int e = tid * 4; e < CD * HD; e += 1024)
        *(f32x4*)&sWa[e] = *(const f32x4*)&Wa[e];

    const float* xb = x + (size_t)p0 * CD;
    const float* yb = y + (size_t)p0 * CD;
#pragma unroll
    for (int i = 0; i < 8; i++) {
        int e = i * 1024 + tid * 4;
        f32x4 xv = *(const f32x4*)&xb[e];
        f32x4 yv = *(const f32x4*)&yb[e];
        int p = e >> 7, c = e & 127;
        float* g = &gbuf[p * 129 + c];
        g[0] = elu_f(xv[0] + yv[0]);
        g[1] = elu_f(xv[1] + yv[1]);
        g[2] = elu_f(xv[2] + yv[2]);
        g[3] = elu_f(xv[3] + yv[3]);
    }
    __syncthreads();

    int p = tid >> 2;
    int h0 = (tid & 3) * 16;
    float facc[16];
#pragma unroll
    for (int j = 0; j < 16; j++) facc[j] = 0.f;
    const float* grow = &gbuf[p * 129];
    for (int c = 0; c < CD; c++) {
        float g = grow[c];
        const float* wr = &sWa[c * HD + h0];
#pragma unroll
        for (int j = 0; j < 16; j++) facc[j] += g * wr[j];
    }
    bf16x8 v0, v1;
#pragma unroll
    for (int j = 0; j < 8; j++) {
        v0[j] = (bf16)elu_f(facc[j]);
        v1[j] = (bf16)elu_f(facc[8 + j]);
    }
    bf16* fp = f + (size_t)(p0 + p) * HD + h0;
    *(bf16x8*)fp = v0;
    *(bf16x8*)(fp + 8) = v1;
}

// ---------------------------------------------------------------------------
// K2: conv (D[o][p] = sum_k WbT_k * gathered f) + fused elu + @Wc + x epilogue
//   256 threads = 4 waves, 64 pts/wave, 256 pts/wg.
//   MFMA 32x32x16 bf16:
//     A-frag: A[m = lane&31][k = (lane>>5)*8 + j]
//     B-frag: B[k = (lane>>5)*8 + j][n = lane&31]
//     D:      col = lane&31, row = (reg&3) + 8*(reg>>2) + 4*(lane>>5)
// ---------------------------------------------------------------------------
__global__ __launch_bounds__(256, 3) void k_conv(const bf16* __restrict__ f,
                                                 const int* __restrict__ nidx,
                                                 const bf16* __restrict__ WbT,
                                                 const bf16* __restrict__ WcT,
                                                 const float* __restrict__ x,
                                                 float* __restrict__ out) {
    __shared__ bf16 wbuf[64 * 64];       // 8 KB  : WbT[k], XOR-swizzled 16B chunks
    __shared__ bf16 wcs[128 * 64];       // 16 KB : WcT, XOR-swizzled
    __shared__ bf16 pbuf[4 * 32 * 64];   // 16 KB : per-wave elu(acc) transpose buf

    int tid = threadIdx.x;
    int wave = tid >> 6;
    int lane = tid & 63;
    int l31 = lane & 31;
    int half = lane >> 5;
    int pbase = blockIdx.x * 256 + wave * 64;

    f32x16 acc[2][2];
#pragma unroll
    for (int a = 0; a < 2; a++)
#pragma unroll
        for (int b = 0; b < 2; b++)
#pragma unroll
            for (int r = 0; r < 16; r++) acc[a][b][r] = 0.f;

    for (int k = 0; k < KEEP; k++) {
        __syncthreads();
        // stage WbT[k] -> wbuf (chunk c of row o stored at (c ^ (o&7)))
#pragma unroll
        for (int L = tid; L < 512; L += 256) {
            int o = L >> 3, ci = L & 7;
            bf16x8 v = *(const bf16x8*)&WbT[(size_t)k * 4096 + L * 8];
            *(bf16x8*)&wbuf[o * 64 + ((ci ^ (o & 7)) * 8)] = v;
        }
        __syncthreads();

        // A-frags (WbT rows = h_out) held in registers for both point-tiles
        bf16x8 af[2][4];
#pragma unroll
        for (int mt = 0; mt < 2; mt++) {
            int o = mt * 32 + l31;
#pragma unroll
            for (int ks = 0; ks < 4; ks++) {
                int ci = 2 * ks + half;
                af[mt][ks] = *(const bf16x8*)&wbuf[o * 64 + ((ci ^ (o & 7)) * 8)];
            }
        }

#pragma unroll
        for (int nt = 0; nt < 2; nt++) {
            int p = pbase + nt * 32 + l31;
            int idxv = (p < N_PTS) ? nidx[(size_t)k * N_PTS + p] : -1;
            bf16x8 bfr[4];
#pragma unroll
            for (int ks = 0; ks < 4; ks++)
#pragma unroll
                for (int j = 0; j < 8; j++) bfr[ks][j] = (bf16)0.f;
            if (idxv >= 0) {
                const bf16* fr = f + (size_t)idxv * HD + half * 8;
#pragma unroll
                for (int ks = 0; ks < 4; ks++)
                    bfr[ks] = *(const bf16x8*)(fr + ks * 16);
            }
#pragma unroll
            for (int ks = 0; ks < 4; ks++)
#pragma unroll
                for (int mt = 0; mt < 2; mt++)
                    acc[mt][nt] = __builtin_amdgcn_mfma_f32_32x32x16_bf16(
                        af[mt][ks], bfr[ks], acc[mt][nt], 0, 0, 0);
        }
    }

    // ---- epilogue: out[p][c] = x[p][c] + elu(acc)^T @ Wc ----
#pragma unroll
    for (int L = tid; L < 1024; L += 256) {
        int c = L >> 3, ci = L & 7;
        bf16x8 v = *(const bf16x8*)&WcT[L * 8];
        *(bf16x8*)&wcs[c * 64 + ((ci ^ (c & 7)) * 8)] = v;
    }
    __syncthreads();

    bf16* pb = &pbuf[wave * 2048];  // per-wave 32 pts x 64 h
#pragma unroll 1
    for (int pt = 0; pt < 2; pt++) {
        // scatter elu(acc[:, pt]) into pbuf as [point][h] bf16 (XOR-swizzled)
#pragma unroll
        for (int mt = 0; mt < 2; mt++) {
#pragma unroll
            for (int q = 0; q < 4; q++) {
                bf16x4 v;
#pragma unroll
                for (int j = 0; j < 4; j++)
                    v[j] = (bf16)elu_f(acc[mt][pt][q * 4 + j]);
                int chunk = mt * 4 + q;  // h = mt*32 + 8q + 4*half + j
                *(bf16x4*)&pb[l31 * 64 + ((chunk ^ (l31 & 7)) * 8) + 4 * half] = v;
            }
        }
        __syncthreads();

        bf16x8 pa[4];
#pragma unroll
        for (int ks = 0; ks < 4; ks++) {
            int ci = 2 * ks + half;
            pa[ks] = *(const bf16x8*)&pb[l31 * 64 + ((ci ^ (l31 & 7)) * 8)];
        }
#pragma unroll 1
        for (int ct = 0; ct < 4; ct++) {
            f32x16 o;
#pragma unroll
            for (int r = 0; r < 16; r++) o[r] = 0.f;
            int cc = ct * 32 + l31;
#pragma unroll
            for (int ks = 0; ks < 4; ks++) {
                int ci = 2 * ks + half;
                bf16x8 bw = *(const bf16x8*)&wcs[cc * 64 + ((ci ^ (cc & 7)) * 8)];
                o = __builtin_amdgcn_mfma_f32_32x32x16_bf16(pa[ks], bw, o, 0, 0, 0);
            }
            int prow_base = pbase + pt * 32 + 4 * half;
#pragma unroll
            for (int r = 0; r < 16; r++) {
                int prow = prow_base + (r & 3) + 8 * (r >> 2);
                if (prow < N_PTS) {
                    size_t off = (size_t)prow * CD + cc;
                    out[off] = x[off] + o[r];
                }
            }
        }
    }
}

// ---------------------------------------------------------------------------
extern "C" void kernel_launch(void* const* d_in, const int* in_sizes, int n_in,
                              void* d_out, int out_size, void* d_ws, size_t ws_size,
                              hipStream_t stream) {
    const float* x  = (const float*)d_in[0];
    const float* y  = (const float*)d_in[1];
    const float* Wa = (const float*)d_in[2];
    const float* Wb = (const float*)d_in[3];
    const float* Wc = (const float*)d_in[4];
    const int* nidx = (const int*)d_in[5];
    float* out = (float*)d_out;

    char* ws = (char*)d_ws;
    bf16* f   = (bf16*)ws;                                // 200192*64*2 = 25,624,576 B
    bf16* WbT = (bf16*)(ws + 25624576);                   // 63*4096*2  =    516,096 B
    bf16* WcT = (bf16*)(ws + 25624576 + 516096);          // 128*64*2   =     16,384 B

    k_prep<<<1040, 256, 0, stream>>>(Wb, Wc, WbT, WcT);
    k_stage1<<<3125, 256, 0, stream>>>(x, y, Wa, f);
    k_conv<<<782, 256, 0, stream>>>(f, nidx, WbT, WcT, x, out);
}

// Round 2
// 781.915 us; speedup vs baseline: 1.7799x; 1.7799x over previous
//
#include <hip/hip_runtime.h>
#include <cmath>

#define N_PTS 200000
#define HD 64
#define CD 128
#define KEEP 63

typedef __bf16 bf16;
typedef __bf16 bf16x4 __attribute__((ext_vector_type(4)));
typedef __bf16 bf16x8 __attribute__((ext_vector_type(8)));
typedef float f32x4 __attribute__((ext_vector_type(4)));
typedef float f32x16 __attribute__((ext_vector_type(16)));

__device__ __forceinline__ float elu_f(float v) { return v > 0.f ? v : expm1f(v); }

// ---------------------------------------------------------------------------
// K0: prep WbT[k][o][i] = Wb[k][i][o] (bf16), WcT[c][h] = Wc[h][c] (bf16)
// ---------------------------------------------------------------------------
__global__ __launch_bounds__(256) void k_prep(const float* __restrict__ Wb,
                                              const float* __restrict__ Wc,
                                              bf16* __restrict__ WbT,
                                              bf16* __restrict__ WcT) {
    int idx = blockIdx.x * 256 + threadIdx.x;
    if (idx < KEEP * HD * HD) {
        int k = idx >> 12;          // /4096
        int rem = idx & 4095;
        int o = rem >> 6, i = rem & 63;
        WbT[idx] = (bf16)Wb[(k * HD + i) * HD + o];
    } else {
        int e = idx - KEEP * HD * HD;
        if (e < CD * HD) {
            int c = e >> 6, h = e & 63;
            WcT[e] = (bf16)Wc[h * CD + c];
        }
    }
}

// ---------------------------------------------------------------------------
// K1: f[n][h] = elu( elu(x[n]+y[n]) @ Wa )  stored as bf16.  64 pts / block.
// ---------------------------------------------------------------------------
__global__ __launch_bounds__(256) void k_stage1(const float* __restrict__ x,
                                                const float* __restrict__ y,
                                                const float* __restrict__ Wa,
                                                bf16* __restrict__ f) {
    __shared__ float sWa[CD * HD];      // 32 KB, [c][h] row-major
    __shared__ float gbuf[64 * 129];    // 33 KB, pad +1 to kill bank conflicts
    int tid = threadIdx.x;
    int p0 = blockIdx.x * 64;

    for (int e = tid * 4; e < CD * HD; e += 1024)
        *(f32x4*)&sWa[e] = *(const f32x4*)&Wa[e];

    const float* xb = x + (size_t)p0 * CD;
    const float* yb = y + (size_t)p0 * CD;
#pragma unroll
    for (int i = 0; i < 8; i++) {
        int e = i * 1024 + tid * 4;
        f32x4 xv = *(const f32x4*)&xb[e];
        f32x4 yv = *(const f32x4*)&yb[e];
        int p = e >> 7, c = e & 127;
        float* g = &gbuf[p * 129 + c];
        g[0] = elu_f(xv[0] + yv[0]);
        g[1] = elu_f(xv[1] + yv[1]);
        g[2] = elu_f(xv[2] + yv[2]);
        g[3] = elu_f(xv[3] + yv[3]);
    }
    __syncthreads();

    int p = tid >> 2;
    int h0 = (tid & 3) * 16;
    float facc[16];
#pragma unroll
    for (int j = 0; j < 16; j++) facc[j] = 0.f;
    const float* grow = &gbuf[p * 129];
    for (int c = 0; c < CD; c++) {
        float g = grow[c];
        const float* wr = &sWa[c * HD + h0];
#pragma unroll
        for (int j = 0; j < 16; j++) facc[j] += g * wr[j];
    }
    bf16x8 v0, v1;
#pragma unroll
    for (int j = 0; j < 8; j++) {
        v0[j] = (bf16)elu_f(facc[j]);
        v1[j] = (bf16)elu_f(facc[8 + j]);
    }
    bf16* fp = f + (size_t)(p0 + p) * HD + h0;
    *(bf16x8*)fp = v0;
    *(bf16x8*)(fp + 8) = v1;
}

// ---------------------------------------------------------------------------
// K2: conv (D[o][p] = sum_k WbT_k * gathered f) + fused elu + @Wc + x epilogue
//   256 threads = 4 waves, 64 pts/wave, 256 pts/wg.
//   Barrier-free main loop: A-frags (WbT) straight from global (L2-resident,
//   broadcast across wgs); B-frags (gathered f rows) straight from global.
//   MFMA 32x32x16 bf16:
//     A-frag: A[m = lane&31][k = (lane>>5)*8 + j]
//     B-frag: B[k = (lane>>5)*8 + j][n = lane&31]
//     D:      col = lane&31, row = (reg&3) + 8*(reg>>2) + 4*(lane>>5)
// ---------------------------------------------------------------------------
__global__ __launch_bounds__(256, 3) void k_conv(const bf16* __restrict__ f,
                                                 const int* __restrict__ nidx,
                                                 const bf16* __restrict__ WbT,
                                                 const bf16* __restrict__ WcT,
                                                 const float* __restrict__ x,
                                                 float* __restrict__ out) {
    __shared__ bf16 wcs[128 * 64];       // 16 KB : WcT, XOR-swizzled
    __shared__ bf16 pbuf[4 * 32 * 64];   // 16 KB : per-wave elu(acc) transpose buf

    int tid = threadIdx.x;
    int wave = tid >> 6;
    int lane = tid & 63;
    int l31 = lane & 31;
    int half = lane >> 5;
    int pbase = blockIdx.x * 256 + wave * 64;

    f32x16 acc[2][2];
#pragma unroll
    for (int a = 0; a < 2; a++)
#pragma unroll
        for (int b = 0; b < 2; b++)
#pragma unroll
            for (int r = 0; r < 16; r++) acc[a][b][r] = 0.f;

    // stage WcT while the main loop runs (no barrier until epilogue)
#pragma unroll
    for (int L = tid; L < 1024; L += 256) {
        int c = L >> 3, ci = L & 7;
        bf16x8 v = *(const bf16x8*)&WcT[L * 8];
        *(bf16x8*)&wcs[c * 64 + ((ci ^ (c & 7)) * 8)] = v;
    }

    for (int k = 0; k < KEEP; k++) {
        const bf16* wk = WbT + (size_t)k * (HD * HD);
        // A-frags (WbT rows = h_out) direct from global: 4x16B per tile, L2-hit
        bf16x8 af[2][4];
#pragma unroll
        for (int mt = 0; mt < 2; mt++) {
            const bf16* wrow = wk + (size_t)(mt * 32 + l31) * HD + half * 8;
#pragma unroll
            for (int ks = 0; ks < 4; ks++)
                af[mt][ks] = *(const bf16x8*)(wrow + ks * 16);
        }

#pragma unroll
        for (int nt = 0; nt < 2; nt++) {
            int p = pbase + nt * 32 + l31;
            int idxv = (p < N_PTS) ? nidx[(size_t)k * N_PTS + p] : -1;
            bf16x8 bfr[4];
#pragma unroll
            for (int ks = 0; ks < 4; ks++)
#pragma unroll
                for (int j = 0; j < 8; j++) bfr[ks][j] = (bf16)0.f;
            if (idxv >= 0) {
                const bf16* fr = f + (size_t)idxv * HD + half * 8;
#pragma unroll
                for (int ks = 0; ks < 4; ks++)
                    bfr[ks] = *(const bf16x8*)(fr + ks * 16);
            }
#pragma unroll
            for (int ks = 0; ks < 4; ks++)
#pragma unroll
                for (int mt = 0; mt < 2; mt++)
                    acc[mt][nt] = __builtin_amdgcn_mfma_f32_32x32x16_bf16(
                        af[mt][ks], bfr[ks], acc[mt][nt], 0, 0, 0);
        }
    }

    __syncthreads();   // wcs staged by all threads, read by all

    // ---- epilogue: out[p][c] = x[p][c] + elu(acc)^T @ Wc ----
    // FULLY UNROLLED pt/ct: every acc index is a compile-time constant
    // (round-1 lesson: runtime-indexed acc => whole accumulator spills to
    // scratch => 3.2 GB of HBM writeback in the main loop).
    bf16* pb = &pbuf[wave * 2048];  // per-wave 32 pts x 64 h
#pragma unroll
    for (int pt = 0; pt < 2; pt++) {
        // scatter elu(acc[:, pt]) into pbuf as [point][h] bf16 (XOR-swizzled)
#pragma unroll
        for (int mt = 0; mt < 2; mt++) {
#pragma unroll
            for (int q = 0; q < 4; q++) {
                bf16x4 v;
#pragma unroll
                for (int j = 0; j < 4; j++)
                    v[j] = (bf16)elu_f(acc[mt][pt][q * 4 + j]);
                int chunk = mt * 4 + q;  // h = mt*32 + 8q + 4*half + j
                *(bf16x4*)&pb[l31 * 64 + ((chunk ^ (l31 & 7)) * 8) + 4 * half] = v;
            }
        }
        // per-wave buffer: same-wave LDS RAW handled by hardware waitcnt,
        // no barrier needed

        bf16x8 pa[4];
#pragma unroll
        for (int ks = 0; ks < 4; ks++) {
            int ci = 2 * ks + half;
            pa[ks] = *(const bf16x8*)&pb[l31 * 64 + ((ci ^ (l31 & 7)) * 8)];
        }
#pragma unroll
        for (int ct = 0; ct < 4; ct++) {
            f32x16 o;
#pragma unroll
            for (int r = 0; r < 16; r++) o[r] = 0.f;
            int cc = ct * 32 + l31;
#pragma unroll
            for (int ks = 0; ks < 4; ks++) {
                int ci = 2 * ks + half;
                bf16x8 bw = *(const bf16x8*)&wcs[cc * 64 + ((ci ^ (cc & 7)) * 8)];
                o = __builtin_amdgcn_mfma_f32_32x32x16_bf16(pa[ks], bw, o, 0, 0, 0);
            }
            int prow_base = pbase + pt * 32 + 4 * half;
#pragma unroll
            for (int r = 0; r < 16; r++) {
                int prow = prow_base + (r & 3) + 8 * (r >> 2);
                if (prow < N_PTS) {
                    size_t off = (size_t)prow * CD + cc;
                    out[off] = x[off] + o[r];
                }
            }
        }
    }
}

// ---------------------------------------------------------------------------
extern "C" void kernel_launch(void* const* d_in, const int* in_sizes, int n_in,
                              void* d_out, int out_size, void* d_ws, size_t ws_size,
                              hipStream_t stream) {
    const float* x  = (const float*)d_in[0];
    const float* y  = (const float*)d_in[1];
    const float* Wa = (const float*)d_in[2];
    const float* Wb = (const float*)d_in[3];
    const float* Wc = (const float*)d_in[4];
    const int* nidx = (const int*)d_in[5];
    float* out = (float*)d_out;

    char* ws = (char*)d_ws;
    bf16* f   = (bf16*)ws;                                // 200192*64*2 = 25,624,576 B
    bf16* WbT = (bf16*)(ws + 25624576);                   // 63*4096*2  =    516,096 B
    bf16* WcT = (bf16*)(ws + 25624576 + 516096);          // 128*64*2   =     16,384 B

    k_prep<<<1040, 256, 0, stream>>>(Wb, Wc, WbT, WcT);
    k_stage1<<<3125, 256, 0, stream>>>(x, y, Wa, f);
    k_conv<<<782, 256, 0, stream>>>(f, nidx, WbT, WcT, x, out);
}

// Round 3
// 695.153 us; speedup vs baseline: 2.0021x; 1.1248x over previous
//
#include <hip/hip_runtime.h>
#include <cmath>

#define N_PTS 200000
#define HD 64
#define CD 128
#define KEEP 63

typedef __bf16 bf16;
typedef __bf16 bf16x4 __attribute__((ext_vector_type(4)));
typedef __bf16 bf16x8 __attribute__((ext_vector_type(8)));
typedef float f32x4 __attribute__((ext_vector_type(4)));
typedef float f32x16 __attribute__((ext_vector_type(16)));

__device__ __forceinline__ float elu_f(float v) {
    return v > 0.f ? v : __expf(v) - 1.f;
}

// ---------------------------------------------------------------------------
// K0: prep WbT[k][o][i]=Wb[k][i][o], WcT[c][h]=Wc[h][c], WaT[o][c]=Wa[c][o],
//     zero-page (128 B of zeros for invalid-neighbor gathers; ws is poisoned
//     0xAA before every launch so this must be re-zeroed each call).
// ---------------------------------------------------------------------------
__global__ __launch_bounds__(256) void k_prep(const float* __restrict__ Wb,
                                              const float* __restrict__ Wc,
                                              const float* __restrict__ Wa,
                                              bf16* __restrict__ WbT,
                                              bf16* __restrict__ WcT,
                                              bf16* __restrict__ WaT,
                                              bf16* __restrict__ zp) {
    int idx = blockIdx.x * 256 + threadIdx.x;
    if (idx < KEEP * HD * HD) {
        int k = idx >> 12;
        int rem = idx & 4095;
        int o = rem >> 6, i = rem & 63;
        WbT[idx] = (bf16)Wb[(k * HD + i) * HD + o];
        return;
    }
    int e = idx - KEEP * HD * HD;
    if (e < CD * HD) {           // WcT
        int c = e >> 6, h = e & 63;
        WcT[e] = (bf16)Wc[h * CD + c];
        return;
    }
    e -= CD * HD;
    if (e < HD * CD) {           // WaT
        int o = e >> 7, c = e & 127;
        WaT[e] = (bf16)Wa[c * HD + o];
        return;
    }
    e -= HD * CD;
    if (e < 64) zp[e] = (bf16)0.f;
}

// ---------------------------------------------------------------------------
// K1: f[n][h] = elu( elu(x[n]+y[n]) @ Wa ), bf16.  MFMA version.
//   4 waves/wg, 32 pts/wave.  B-frag = elu(x+y) computed in-register from
//   row-major x,y (8 k-contiguous elems = 2x f32x4 loads).  A = WaT from
//   global (L2-broadcast, 16 KB total).
// ---------------------------------------------------------------------------
__global__ __launch_bounds__(256, 4) void k_stage1(const float* __restrict__ x,
                                                   const float* __restrict__ y,
                                                   const bf16* __restrict__ WaT,
                                                   bf16* __restrict__ f) {
    __shared__ bf16 pbuf[4][32 * 64];   // 16 KB, per-wave transpose buffer
    int tid = threadIdx.x;
    int wave = tid >> 6;
    int lane = tid & 63;
    int l31 = lane & 31;
    int half = lane >> 5;
    int pbase_w = blockIdx.x * 128 + wave * 32;
    int p = pbase_w + l31;
    int pc = p < N_PTS ? p : N_PTS - 1;     // clamp loads; stores guarded

    const float* xr = x + (size_t)pc * CD;
    const float* yr = y + (size_t)pc * CD;

    f32x16 acc[2];
#pragma unroll
    for (int mt = 0; mt < 2; mt++)
#pragma unroll
        for (int r = 0; r < 16; r++) acc[mt][r] = 0.f;

#pragma unroll
    for (int ks = 0; ks < 8; ks++) {
        int c0 = half * 8 + ks * 16;
        f32x4 xa = *(const f32x4*)(xr + c0);
        f32x4 xb = *(const f32x4*)(xr + c0 + 4);
        f32x4 ya = *(const f32x4*)(yr + c0);
        f32x4 yb = *(const f32x4*)(yr + c0 + 4);
        bf16x8 bv;
#pragma unroll
        for (int j = 0; j < 4; j++) {
            bv[j]     = (bf16)elu_f(xa[j] + ya[j]);
            bv[4 + j] = (bf16)elu_f(xb[j] + yb[j]);
        }
#pragma unroll
        for (int mt = 0; mt < 2; mt++) {
            bf16x8 a = *(const bf16x8*)(WaT + (size_t)(mt * 32 + l31) * CD + c0);
            acc[mt] = __builtin_amdgcn_mfma_f32_32x32x16_bf16(a, bv, acc[mt], 0, 0, 0);
        }
    }

    // elu + scatter into pbuf [point][h] (XOR-swizzled 16B chunks), then
    // coalesced 16B stores.  Per-wave buffer: no barrier needed.
    bf16* pb = pbuf[wave];
#pragma unroll
    for (int mt = 0; mt < 2; mt++) {
#pragma unroll
        for (int q = 0; q < 4; q++) {
            bf16x4 v;
#pragma unroll
            for (int j = 0; j < 4; j++)
                v[j] = (bf16)elu_f(acc[mt][q * 4 + j]);
            int chunk = mt * 4 + q;   // h = chunk*8 + 4*half + j
            *(bf16x4*)&pb[l31 * 64 + ((chunk ^ (l31 & 7)) * 8) + 4 * half] = v;
        }
    }
#pragma unroll
    for (int qq = 0; qq < 4; qq++) {
        int t = lane + 64 * qq;          // 0..255 chunk ids
        int row = t >> 3, ch = t & 7;
        int pos = ch ^ (row & 7);
        bf16x8 v = *(const bf16x8*)&pb[row * 64 + pos * 8];
        int pp = pbase_w + row;
        if (pp < N_PTS)
            *(bf16x8*)(f + (size_t)pp * HD + ch * 8) = v;
    }
}

// ---------------------------------------------------------------------------
// K2: conv + fused epilogue.  64 pts/wave, 4 waves/wg.
//   Software-pipelined, branchless main loop:
//     - invalid neighbors gather from a 128B zero-page (exact 0 contribution)
//     - B-frags triple-buffered: gather for k+2 issued during MFMA of k
//     - nidx prefetched 5-7 iterations ahead in rotating registers
//     - A-frags (WbT) direct from global, L2-broadcast
//   63 = 21*3: unroll-by-3, static buffer rotation, no runtime indexing.
// ---------------------------------------------------------------------------
struct BB { bf16x8 v[4]; };

__global__ __launch_bounds__(256, 2) void k_conv(const bf16* __restrict__ f,
                                                 const int* __restrict__ nidx,
                                                 const bf16* __restrict__ WbT,
                                                 const bf16* __restrict__ WcT,
                                                 const bf16* __restrict__ zp,
                                                 const float* __restrict__ x,
                                                 float* __restrict__ out) {
    __shared__ bf16 wcs[128 * 64];       // 16 KB : WcT, XOR-swizzled
    __shared__ bf16 pbuf[4 * 32 * 64];   // 16 KB : per-wave transpose buf

    int tid = threadIdx.x;
    int wave = tid >> 6;
    int lane = tid & 63;
    int l31 = lane & 31;
    int half = lane >> 5;
    int pbase = blockIdx.x * 256 + wave * 64;
    int p0 = pbase + l31;
    int p1 = pbase + 32 + l31;

    f32x16 acc[2][2];
#pragma unroll
    for (int a = 0; a < 2; a++)
#pragma unroll
        for (int b = 0; b < 2; b++)
#pragma unroll
            for (int r = 0; r < 16; r++) acc[a][b][r] = 0.f;

    // stage WcT (consumed after the one barrier before the epilogue)
#pragma unroll
    for (int L = tid; L < 1024; L += 256) {
        int c = L >> 3, ci = L & 7;
        bf16x8 v = *(const bf16x8*)&WcT[L * 8];
        *(bf16x8*)&wcs[c * 64 + ((ci ^ (c & 7)) * 8)] = v;
    }

    auto ldidx = [&](int k, int pp) -> int {
        return (k < KEEP && pp < N_PTS) ? nidx[(size_t)k * N_PTS + pp] : -1;
    };
    auto baddr = [&](int iv) -> const bf16* {
        return iv >= 0 ? f + (size_t)iv * HD + half * 8 : zp + half * 8;
    };
    auto gather = [&](BB& b, const bf16* a) {
#pragma unroll
        for (int ks = 0; ks < 4; ks++)
            b.v[ks] = *(const bf16x8*)(a + ks * 16);
    };
    auto step = [&](int k, BB& q0, BB& q1) {
        const bf16* wk = WbT + (size_t)k * (HD * HD);
#pragma unroll
        for (int ks = 0; ks < 4; ks++) {
#pragma unroll
            for (int mt = 0; mt < 2; mt++) {
                bf16x8 a = *(const bf16x8*)(wk + (size_t)(mt * 32 + l31) * HD +
                                            half * 8 + ks * 16);
                acc[mt][0] = __builtin_amdgcn_mfma_f32_32x32x16_bf16(a, q0.v[ks], acc[mt][0], 0, 0, 0);
                acc[mt][1] = __builtin_amdgcn_mfma_f32_32x32x16_bf16(a, q1.v[ks], acc[mt][1], 0, 0, 0);
            }
        }
    };

    // prologue: B slots b0=k0, b1=k1; idx slots: s2=k2, s0=k3, s1=k4
    BB b0a, b0b, b1a, b1b, b2a, b2b;
    int i2a = ldidx(2, p0), i2b = ldidx(2, p1);
    int i0a = ldidx(3, p0), i0b = ldidx(3, p1);
    int i1a = ldidx(4, p0), i1b = ldidx(4, p1);
    {
        int ja = ldidx(0, p0), jb = ldidx(0, p1);
        int ka = ldidx(1, p0), kb = ldidx(1, p1);
        gather(b0a, baddr(ja)); gather(b0b, baddr(jb));
        gather(b1a, baddr(ka)); gather(b1b, baddr(kb));
    }

    // invariant entering body j (k=3j): b0=k, b1=k+1, idx slots k+2,k+3,k+4
    for (int j = 0; j < 20; j++) {
        int k = 3 * j;
        gather(b2a, baddr(i2a)); gather(b2b, baddr(i2b));   // k+2
        i2a = ldidx(k + 5, p0);  i2b = ldidx(k + 5, p1);
        step(k, b0a, b0b);
        gather(b0a, baddr(i0a)); gather(b0b, baddr(i0b));   // k+3
        i0a = ldidx(k + 6, p0);  i0b = ldidx(k + 6, p1);
        step(k + 1, b1a, b1b);
        gather(b1a, baddr(i1a)); gather(b1b, baddr(i1b));   // k+4
        i1a = ldidx(k + 7, p0);  i1b = ldidx(k + 7, p1);
        step(k + 2, b2a, b2b);
    }
    // tail: b0=60, b1=61, s2 holds idx for 62
    gather(b2a, baddr(i2a)); gather(b2b, baddr(i2b));
    step(60, b0a, b0b);
    step(61, b1a, b1b);
    step(62, b2a, b2b);

    __syncthreads();   // wcs visibility

    // ---- epilogue: out[p][c] = x[p][c] + elu(acc)^T @ Wc ----
    // fully unrolled; all acc indices compile-time (round-1 lesson)
    bf16* pb = &pbuf[wave * 2048];
#pragma unroll
    for (int pt = 0; pt < 2; pt++) {
#pragma unroll
        for (int mt = 0; mt < 2; mt++) {
#pragma unroll
            for (int q = 0; q < 4; q++) {
                bf16x4 v;
#pragma unroll
                for (int j = 0; j < 4; j++)
                    v[j] = (bf16)elu_f(acc[mt][pt][q * 4 + j]);
                int chunk = mt * 4 + q;
                *(bf16x4*)&pb[l31 * 64 + ((chunk ^ (l31 & 7)) * 8) + 4 * half] = v;
            }
        }
        // per-wave buffer: same-wave LDS RAW handled by waitcnt, no barrier
        bf16x8 pa[4];
#pragma unroll
        for (int ks = 0; ks < 4; ks++) {
            int ci = 2 * ks + half;
            pa[ks] = *(const bf16x8*)&pb[l31 * 64 + ((ci ^ (l31 & 7)) * 8)];
        }
#pragma unroll
        for (int ct = 0; ct < 4; ct++) {
            f32x16 o;
#pragma unroll
            for (int r = 0; r < 16; r++) o[r] = 0.f;
            int cc = ct * 32 + l31;
#pragma unroll
            for (int ks = 0; ks < 4; ks++) {
                int ci = 2 * ks + half;
                bf16x8 bw = *(const bf16x8*)&wcs[cc * 64 + ((ci ^ (cc & 7)) * 8)];
                o = __builtin_amdgcn_mfma_f32_32x32x16_bf16(pa[ks], bw, o, 0, 0, 0);
            }
            int prow_base = pbase + pt * 32 + 4 * half;
#pragma unroll
            for (int r = 0; r < 16; r++) {
                int prow = prow_base + (r & 3) + 8 * (r >> 2);
                if (prow < N_PTS) {
                    size_t off = (size_t)prow * CD + cc;
                    out[off] = x[off] + o[r];
                }
            }
        }
    }
}

// ---------------------------------------------------------------------------
extern "C" void kernel_launch(void* const* d_in, const int* in_sizes, int n_in,
                              void* d_out, int out_size, void* d_ws, size_t ws_size,
                              hipStream_t stream) {
    const float* x  = (const float*)d_in[0];
    const float* y  = (const float*)d_in[1];
    const float* Wa = (const float*)d_in[2];
    const float* Wb = (const float*)d_in[3];
    const float* Wc = (const float*)d_in[4];
    const int* nidx = (const int*)d_in[5];
    float* out = (float*)d_out;

    char* ws = (char*)d_ws;
    bf16* f   = (bf16*)ws;                           // 200192*64*2 = 25,624,576 B
    bf16* WbT = (bf16*)(ws + 25624576);              // 63*4096*2   =    516,096 B
    bf16* WcT = (bf16*)(ws + 25624576 + 516096);     // 8192*2      =     16,384 B
    bf16* WaT = (bf16*)(ws + 25624576 + 516096 + 16384);   // 8192*2 = 16,384 B
    bf16* zp  = (bf16*)(ws + 25624576 + 516096 + 16384 + 16384);  // 128 B zeros

    k_prep<<<1073, 256, 0, stream>>>(Wb, Wc, Wa, WbT, WcT, WaT, zp);
    k_stage1<<<1564, 256, 0, stream>>>(x, y, WaT, f);
    k_conv<<<782, 256, 0, stream>>>(f, nidx, WbT, WcT, zp, x, out);
}